// Round 1
// baseline (2965.544 us; speedup 1.0000x reference)
//
#include <hip/hip_runtime.h>
#include <hip/hip_bf16.h>

#define N_NODES 100000
#define N_EDGES 800000
#define HIDDEN  128

typedef __attribute__((ext_vector_type(8))) short bf16x8;
typedef __attribute__((ext_vector_type(4))) float f32x4;

__device__ __forceinline__ short f2bf(float f) {
  union { float f; unsigned u; } x; x.f = f;
  unsigned r = x.u + 0x7fffu + ((x.u >> 16) & 1u);   // RNE
  return (short)(r >> 16);
}

__device__ __forceinline__ bf16x8 cvt8(f32x4 lo, f32x4 hi) {
  bf16x8 r;
#pragma unroll
  for (int j = 0; j < 4; j++) { r[j] = f2bf(lo[j]); r[j + 4] = f2bf(hi[j]); }
  return r;
}

// Convert the three weight matrices to bf16 once per launch.
// Layout in out: [0]=Ws_w (pairs with h), [1]=W_w (pairs with aggF), [2]=Wt_w (pairs with aggB)
__global__ __launch_bounds__(256) void convert_weights(
    const float* __restrict__ m0, const float* __restrict__ m1,
    const float* __restrict__ m2, short* __restrict__ out) {
  int i = blockIdx.x * 256 + threadIdx.x;   // [0, 3*16384)
  int m = i >> 14, j = i & 16383;
  const float* s = (m == 0) ? m0 : (m == 1) ? m1 : m2;
  out[i] = f2bf(s[j]);
}

// One 32-lane half... actually: each 32-thread group handles one edge-direction.
// aggF[src] += h[dst]; degF[src]++    (forward:  A @ h)
// aggB[dst] += h[src]; degB[dst]++    (backward: A.T @ h)
__global__ __launch_bounds__(256) void scatter_kernel(
    const float* __restrict__ h,
    const int* __restrict__ esrc, const int* __restrict__ edst,
    float* __restrict__ aggF, float* __restrict__ aggB,
    int* __restrict__ degF, int* __restrict__ degB) {
  unsigned gtid = blockIdx.x * 256u + threadIdx.x;
  unsigned ed = gtid >> 5;     // edge-direction index in [0, 2*N_EDGES)
  unsigned q  = gtid & 31u;    // which 4-float chunk of the 128-wide row
  if (ed >= 2u * N_EDGES) return;
  int tgt, srcn;
  float* agg;
  int* deg;
  if (ed < N_EDGES) {
    tgt = esrc[ed]; srcn = edst[ed]; agg = aggF; deg = degF;
  } else {
    unsigned e = ed - N_EDGES;
    tgt = edst[e]; srcn = esrc[e]; agg = aggB; deg = degB;
  }
  f32x4 v = *(const f32x4*)(h + (size_t)srcn * HIDDEN + q * 4);
  float* dst = agg + (size_t)tgt * HIDDEN + q * 4;
  unsafeAtomicAdd(dst + 0, v[0]);
  unsafeAtomicAdd(dst + 1, v[1]);
  unsafeAtomicAdd(dst + 2, v[2]);
  unsafeAtomicAdd(dst + 3, v[3]);
  if (q == 0) atomicAdd(deg + tgt, 1);
}

// Fused: out = relu( h@Ws^T + aggF@W^T + aggB@Wt^T + Ws_b + degF*W_b + degB*Wt_b )
// Per block: 256 threads = 4 waves, M-tile = 64 rows (16 per wave), N = K = 128.
// 16x16x32 bf16 MFMA. A-frag: lane holds A[m=lane&15][kq*8..+8] (kq=lane>>4) -> read
// 32B contiguous fp32 from global and convert. B-frag: lane holds B[k][n]=W[n][k] for
// n=lane&15, k=kq*8..+8 -> 16B contiguous bf16 row of the pre-converted weights.
// C/D: col=lane&15, row=(lane>>4)*4+reg  [guide-verified mapping].
__global__ __launch_bounds__(256) void gemm_fused(
    const float* __restrict__ h, const float* __restrict__ aggF,
    const float* __restrict__ aggB, const short* __restrict__ Wbf,
    const float* __restrict__ Wb, const float* __restrict__ Wsb,
    const float* __restrict__ Wtb,
    const int* __restrict__ degF, const int* __restrict__ degB,
    float* __restrict__ out) {
  int wave = threadIdx.x >> 6;
  int lane = threadIdx.x & 63;
  int m16  = lane & 15;
  int kq   = lane >> 4;
  int tile_row0 = blockIdx.x * 64 + wave * 16;
  int arow = tile_row0 + m16;
  bool arow_ok = arow < N_NODES;

  const float* aptr[3] = { h, aggF, aggB };
  bf16x8 afrag[3][4];
#pragma unroll
  for (int i = 0; i < 3; i++) {
    const float* base = aptr[i] + (size_t)arow * HIDDEN + kq * 8;
#pragma unroll
    for (int t = 0; t < 4; t++) {
      if (arow_ok) {
        f32x4 lo = *(const f32x4*)(base + t * 32);
        f32x4 hi = *(const f32x4*)(base + t * 32 + 4);
        afrag[i][t] = cvt8(lo, hi);
      } else {
        bf16x8 z;
#pragma unroll
        for (int j = 0; j < 8; j++) z[j] = 0;
        afrag[i][t] = z;
      }
    }
  }

  // C rows handled by this lane (same for every N-tile)
  int crow0 = tile_row0 + kq * 4;
  float dF[4], dB[4];
#pragma unroll
  for (int j = 0; j < 4; j++) {
    int r = crow0 + j;
    dF[j] = (r < N_NODES) ? (float)degF[r] : 0.f;
    dB[j] = (r < N_NODES) ? (float)degB[r] : 0.f;
  }

#pragma unroll
  for (int nt = 0; nt < 8; nt++) {
    int col = nt * 16 + m16;
    f32x4 acc = { 0.f, 0.f, 0.f, 0.f };
#pragma unroll
    for (int i = 0; i < 3; i++) {
      const short* wb = Wbf + i * 16384 + col * HIDDEN + kq * 8;
#pragma unroll
      for (int t = 0; t < 4; t++) {
        bf16x8 bfrag = *(const bf16x8*)(wb + t * 32);
        acc = __builtin_amdgcn_mfma_f32_16x16x32_bf16(afrag[i][t], bfrag, acc, 0, 0, 0);
      }
    }
    float bW = Wb[col], bS = Wsb[col], bT = Wtb[col];
#pragma unroll
    for (int j = 0; j < 4; j++) {
      int r = crow0 + j;
      if (r < N_NODES) {
        float v = acc[j] + bS + dF[j] * bW + dB[j] * bT;
        out[(size_t)r * HIDDEN + col] = fmaxf(v, 0.f);
      }
    }
  }
}

extern "C" void kernel_launch(void* const* d_in, const int* in_sizes, int n_in,
                              void* d_out, int out_size, void* d_ws, size_t ws_size,
                              hipStream_t stream) {
  const float* h   = (const float*)d_in[0];
  const int*   esrc = (const int*)d_in[1];
  const int*   edst = (const int*)d_in[2];
  const float* Ww  = (const float*)d_in[3];
  const float* Wb  = (const float*)d_in[4];
  const float* Wsw = (const float*)d_in[5];
  const float* Wsb = (const float*)d_in[6];
  const float* Wtw = (const float*)d_in[7];
  const float* Wtb = (const float*)d_in[8];
  float* out = (float*)d_out;

  char* ws = (char*)d_ws;
  const size_t AGG_BYTES = (size_t)N_NODES * HIDDEN * sizeof(float);   // 51,200,000
  float* aggF = (float*)(ws);
  float* aggB = (float*)(ws + AGG_BYTES);
  int*   degF = (int*)(ws + 2 * AGG_BYTES);
  int*   degB = (int*)(ws + 2 * AGG_BYTES + (size_t)N_NODES * 4);
  short* Wbf  = (short*)(ws + 2 * AGG_BYTES + 2 * (size_t)N_NODES * 4);

  // zero agg + deg regions (ws is poisoned 0xAA before every timed launch)
  hipMemsetAsync(ws, 0, 2 * AGG_BYTES + 2 * (size_t)N_NODES * 4, stream);

  convert_weights<<<(3 * 16384) / 256, 256, 0, stream>>>(Wsw, Ww, Wtw, Wbf);

  // 2*N_EDGES edge-directions, 32 threads each
  scatter_kernel<<<(2 * N_EDGES * 32) / 256, 256, 0, stream>>>(
      h, esrc, edst, aggF, aggB, degF, degB);

  gemm_fused<<<(N_NODES + 63) / 64, 256, 0, stream>>>(
      h, aggF, aggB, Wbf, Wb, Wsb, Wtb, degF, degB, out);
}

// Round 2
// 513.749 us; speedup vs baseline: 5.7724x; 5.7724x over previous
//
#include <hip/hip_runtime.h>
#include <hip/hip_bf16.h>

#define NN 100000
#define NE 800000
#define HIDDEN 128

typedef __attribute__((ext_vector_type(8))) short bf16x8;
typedef __attribute__((ext_vector_type(4))) short bf16x4;
typedef __attribute__((ext_vector_type(4))) float f32x4;

__device__ __forceinline__ short f2bf(float f) {
  union { float f; unsigned u; } x; x.f = f;
  unsigned r = x.u + 0x7fffu + ((x.u >> 16) & 1u);   // RNE
  return (short)(r >> 16);
}

// ---- weights fp32 -> bf16 (order: [0]=Ws_w, [1]=W_w, [2]=Wt_w) ----
__global__ __launch_bounds__(256) void convert_weights(
    const float* __restrict__ m0, const float* __restrict__ m1,
    const float* __restrict__ m2, short* __restrict__ out) {
  int i = blockIdx.x * 256 + threadIdx.x;   // [0, 3*16384)
  int m = i >> 14, j = i & 16383;
  const float* s = (m == 0) ? m0 : (m == 1) ? m1 : m2;
  out[i] = f2bf(s[j]);
}

// ---- 1. degree histogram: deg[0..NN)=out-deg(src), deg[NN..2NN)=in-deg(dst) ----
__global__ __launch_bounds__(256) void hist_kernel(
    const int* __restrict__ esrc, const int* __restrict__ edst,
    int* __restrict__ deg) {
  int e = blockIdx.x * 256 + threadIdx.x;
  if (e >= NE) return;
  atomicAdd(deg + esrc[e], 1);
  atomicAdd(deg + NN + edst[e], 1);
}

// ---- 2. two-level exclusive scan over deg[0..2NN) -> cur ----
#define SCAN_M (2 * NN)
#define SCAN_B 1024
#define SCAN_G ((SCAN_M + SCAN_B - 1) / SCAN_B)   // 196

__global__ __launch_bounds__(SCAN_B) void scanA(
    const int* __restrict__ deg, int* __restrict__ cur, int* __restrict__ bsums) {
  __shared__ int lds[SCAN_B];
  int tid = threadIdx.x;
  int i = blockIdx.x * SCAN_B + tid;
  int v = (i < SCAN_M) ? deg[i] : 0;
  lds[tid] = v; __syncthreads();
#pragma unroll
  for (int off = 1; off < SCAN_B; off <<= 1) {
    int t = lds[tid];
    int add = (tid >= off) ? lds[tid - off] : 0;
    __syncthreads();
    lds[tid] = t + add;
    __syncthreads();
  }
  if (i < SCAN_M) cur[i] = lds[tid];               // local inclusive
  if (tid == SCAN_B - 1) bsums[blockIdx.x] = lds[tid];
}

__global__ __launch_bounds__(256) void scanB_k(int* __restrict__ bsums) {
  __shared__ int lds[256];
  int tid = threadIdx.x;
  int v = (tid < SCAN_G) ? bsums[tid] : 0;
  lds[tid] = v; __syncthreads();
#pragma unroll
  for (int off = 1; off < 256; off <<= 1) {
    int t = lds[tid];
    int add = (tid >= off) ? lds[tid - off] : 0;
    __syncthreads();
    lds[tid] = t + add;
    __syncthreads();
  }
  if (tid < SCAN_G) bsums[tid] = lds[tid] - v;     // exclusive
}

__global__ __launch_bounds__(SCAN_B) void scanC(
    const int* __restrict__ deg, int* __restrict__ cur, const int* __restrict__ bsums) {
  int i = blockIdx.x * SCAN_B + threadIdx.x;
  if (i < SCAN_M) cur[i] = cur[i] - deg[i] + bsums[blockIdx.x];  // global exclusive
}

// ---- 3. fill CSR adjacency (EL[0..NE)=fwd lists, EL[NE..2NE)=bwd lists) ----
__global__ __launch_bounds__(256) void fill_kernel(
    const int* __restrict__ esrc, const int* __restrict__ edst,
    int* __restrict__ cur, int* __restrict__ EL) {
  int e = blockIdx.x * 256 + threadIdx.x;
  if (e >= NE) return;
  int s = esrc[e], d = edst[e];
  int pF = atomicAdd(cur + s, 1);       EL[pF] = d;
  int pB = atomicAdd(cur + NN + d, 1);  EL[pB] = s;
}

// ---- 4. gather-reduce: 32 lanes per node-direction, no float atomics ----
// After fill, cur[nd] = segment end; start = end - deg[nd]. Output bf16.
__global__ __launch_bounds__(256) void gather_kernel(
    const float* __restrict__ h, const int* __restrict__ EL,
    const int* __restrict__ cur, const int* __restrict__ deg,
    short* __restrict__ aggF, short* __restrict__ aggB) {
  unsigned gt = blockIdx.x * 256u + threadIdx.x;
  unsigned nd = gt >> 5;
  unsigned q  = gt & 31u;
  if (nd >= 2u * NN) return;
  int end = cur[nd];
  int j = end - deg[nd];
  f32x4 acc = {0.f, 0.f, 0.f, 0.f};
  if (j < end) {
    int nbr = EL[j];
    while (++j < end) {
      int nxt = EL[j];
      f32x4 v = *(const f32x4*)(h + (size_t)nbr * HIDDEN + q * 4);
      acc[0] += v[0]; acc[1] += v[1]; acc[2] += v[2]; acc[3] += v[3];
      nbr = nxt;
    }
    f32x4 v = *(const f32x4*)(h + (size_t)nbr * HIDDEN + q * 4);
    acc[0] += v[0]; acc[1] += v[1]; acc[2] += v[2]; acc[3] += v[3];
  }
  bf16x4 o;
#pragma unroll
  for (int t = 0; t < 4; t++) o[t] = f2bf(acc[t]);
  short* dst = ((nd < NN) ? aggF + (size_t)nd * HIDDEN
                          : aggB + (size_t)(nd - NN) * HIDDEN) + q * 4;
  *(bf16x4*)dst = o;
}

// ---- 5. fused GEMM epilogue ----
// out = relu( h@Ws^T + aggF@W^T + aggB@Wt^T + Ws_b + degF*W_b + degB*Wt_b )
// 4 waves/block, 64-row M-tile, 16x16x32 bf16 MFMA, weights register/L1-resident.
__global__ __launch_bounds__(256) void gemm_fused(
    const float* __restrict__ h, const short* __restrict__ aggF,
    const short* __restrict__ aggB, const short* __restrict__ Wbf,
    const float* __restrict__ Wb, const float* __restrict__ Wsb,
    const float* __restrict__ Wtb, const int* __restrict__ deg,
    float* __restrict__ out) {
  int wave = threadIdx.x >> 6;
  int lane = threadIdx.x & 63;
  int m16  = lane & 15;
  int kq   = lane >> 4;
  int tile_row0 = blockIdx.x * 64 + wave * 16;
  int arow = tile_row0 + m16;
  bool arow_ok = arow < NN;

  bf16x8 afH[4], afF[4], afB[4];
  bf16x8 z;
#pragma unroll
  for (int j = 0; j < 8; j++) z[j] = 0;

  const float* hb = h + (size_t)arow * HIDDEN + kq * 8;
  const short* fb = aggF + (size_t)arow * HIDDEN + kq * 8;
  const short* bb = aggB + (size_t)arow * HIDDEN + kq * 8;
#pragma unroll
  for (int t = 0; t < 4; t++) {
    if (arow_ok) {
      f32x4 lo = *(const f32x4*)(hb + t * 32);
      f32x4 hi = *(const f32x4*)(hb + t * 32 + 4);
      bf16x8 r;
#pragma unroll
      for (int j = 0; j < 4; j++) { r[j] = f2bf(lo[j]); r[j + 4] = f2bf(hi[j]); }
      afH[t] = r;
      afF[t] = *(const bf16x8*)(fb + t * 32);
      afB[t] = *(const bf16x8*)(bb + t * 32);
    } else {
      afH[t] = z; afF[t] = z; afB[t] = z;
    }
  }

  int crow0 = tile_row0 + kq * 4;
  float dF[4], dB[4];
#pragma unroll
  for (int j = 0; j < 4; j++) {
    int r = crow0 + j;
    dF[j] = (r < NN) ? (float)deg[r] : 0.f;
    dB[j] = (r < NN) ? (float)deg[NN + r] : 0.f;
  }

#pragma unroll
  for (int nt = 0; nt < 8; nt++) {
    int col = nt * 16 + m16;
    f32x4 acc = {0.f, 0.f, 0.f, 0.f};
    const short* w0 = Wbf + 0 * 16384 + col * HIDDEN + kq * 8;
    const short* w1 = Wbf + 1 * 16384 + col * HIDDEN + kq * 8;
    const short* w2 = Wbf + 2 * 16384 + col * HIDDEN + kq * 8;
#pragma unroll
    for (int t = 0; t < 4; t++)
      acc = __builtin_amdgcn_mfma_f32_16x16x32_bf16(afH[t], *(const bf16x8*)(w0 + t * 32), acc, 0, 0, 0);
#pragma unroll
    for (int t = 0; t < 4; t++)
      acc = __builtin_amdgcn_mfma_f32_16x16x32_bf16(afF[t], *(const bf16x8*)(w1 + t * 32), acc, 0, 0, 0);
#pragma unroll
    for (int t = 0; t < 4; t++)
      acc = __builtin_amdgcn_mfma_f32_16x16x32_bf16(afB[t], *(const bf16x8*)(w2 + t * 32), acc, 0, 0, 0);

    float bW = Wb[col], bS = Wsb[col], bT = Wtb[col];
#pragma unroll
    for (int j = 0; j < 4; j++) {
      int r = crow0 + j;
      if (r < NN) {
        float v = acc[j] + bS + dF[j] * bW + dB[j] * bT;
        out[(size_t)r * HIDDEN + col] = fmaxf(v, 0.f);
      }
    }
  }
}

extern "C" void kernel_launch(void* const* d_in, const int* in_sizes, int n_in,
                              void* d_out, int out_size, void* d_ws, size_t ws_size,
                              hipStream_t stream) {
  const float* h    = (const float*)d_in[0];
  const int*   esrc = (const int*)d_in[1];
  const int*   edst = (const int*)d_in[2];
  const float* Ww   = (const float*)d_in[3];
  const float* Wb   = (const float*)d_in[4];
  const float* Wsw  = (const float*)d_in[5];
  const float* Wsb  = (const float*)d_in[6];
  const float* Wtw  = (const float*)d_in[7];
  const float* Wtb  = (const float*)d_in[8];
  float* out = (float*)d_out;

  char* ws = (char*)d_ws;
  // layout (bytes)
  int*   deg   = (int*)(ws + 0);                         //   800,000
  int*   cur   = (int*)(ws + 800000);                    //   800,000
  int*   bsums = (int*)(ws + 1600000);                   //     1,024
  int*   EL    = (int*)(ws + 1601024);                   // 6,400,000
  short* Wbf   = (short*)(ws + 8001024);                 //    98,304
  short* aggF  = (short*)(ws + 8099840);                 // 25,600,000
  short* aggB  = (short*)(ws + 33699840);                // 25,600,000  -> total ~59.3 MB

  hipMemsetAsync(deg, 0, 2 * NN * sizeof(int), stream);

  convert_weights<<<192, 256, 0, stream>>>(Wsw, Ww, Wtw, Wbf);
  hist_kernel<<<(NE + 255) / 256, 256, 0, stream>>>(esrc, edst, deg);
  scanA<<<SCAN_G, SCAN_B, 0, stream>>>(deg, cur, bsums);
  scanB_k<<<1, 256, 0, stream>>>(bsums);
  scanC<<<SCAN_G, SCAN_B, 0, stream>>>(deg, cur, bsums);
  fill_kernel<<<(NE + 255) / 256, 256, 0, stream>>>(esrc, edst, cur, EL);
  gather_kernel<<<(2 * NN * 32) / 256, 256, 0, stream>>>(h, EL, cur, deg, aggF, aggB);
  gemm_fused<<<(NN + 63) / 64, 256, 0, stream>>>(
      h, aggF, aggB, Wbf, Wb, Wsb, Wtb, deg, out);
}

// Round 3
// 510.807 us; speedup vs baseline: 5.8056x; 1.0058x over previous
//
#include <hip/hip_runtime.h>
#include <hip/hip_bf16.h>

#define NN 100000
#define NE 800000
#define HIDDEN 128
#define NREP 8                      // cursor/degree replicas (contention split)
#define SCAN_M (2 * NN)             // node-directions: [0,NN)=fwd(src), [NN,2NN)=bwd(dst)
#define SCAN_B 1024
#define SCAN_G ((SCAN_M + SCAN_B - 1) / SCAN_B)   // 196
#define EBLK 3125                   // NE / 256, exact

typedef __attribute__((ext_vector_type(8))) short bf16x8;
typedef __attribute__((ext_vector_type(4))) short bf16x4;
typedef __attribute__((ext_vector_type(4))) float f32x4;

__device__ __forceinline__ short f2bf(float f) {
  union { float f; unsigned u; } x; x.f = f;
  unsigned r = x.u + 0x7fffu + ((x.u >> 16) & 1u);   // RNE
  return (short)(r >> 16);
}

// ---- weights fp32 -> bf16 (order: [0]=Ws_w, [1]=W_w, [2]=Wt_w) ----
__global__ __launch_bounds__(256) void convert_weights(
    const float* __restrict__ m0, const float* __restrict__ m1,
    const float* __restrict__ m2, short* __restrict__ out) {
  int i = blockIdx.x * 256 + threadIdx.x;   // [0, 3*16384)
  int m = i >> 14, j = i & 16383;
  const float* s = (m == 0) ? m0 : (m == 1) ? m1 : m2;
  out[i] = f2bf(s[j]);
}

// ---- 1. replicated degree histogram ----
// Replica choice must match fill_kernel's per-edge-direction mapping:
// fwd direction ed=e -> r=(e>>8)&7 ; bwd direction ed=NE+e -> r=((e>>8)+EBLK)&7
// (exact since NE == EBLK*256).
__global__ __launch_bounds__(256) void hist_kernel(
    const int* __restrict__ esrc, const int* __restrict__ edst,
    int* __restrict__ deg_r) {
  int e = blockIdx.x * 256 + threadIdx.x;          // grid exact: EBLK blocks
  unsigned b = (unsigned)e >> 8;
  int rf = b & (NREP - 1);
  int rb = (b + EBLK) & (NREP - 1);
  atomicAdd(deg_r + rf * SCAN_M + esrc[e], 1);          // non-returning
  atomicAdd(deg_r + rb * SCAN_M + NN + edst[e], 1);
}

// ---- 2. scan: degT = sum over replicas; seg_start = exclusive scan(degT) ----
__global__ __launch_bounds__(SCAN_B) void scanA(
    const int* __restrict__ deg_r, int* __restrict__ degT,
    int* __restrict__ seg_start, int* __restrict__ bsums) {
  __shared__ int lds[SCAN_B];
  int tid = threadIdx.x;
  int i = blockIdx.x * SCAN_B + tid;
  int v = 0;
  if (i < SCAN_M) {
#pragma unroll
    for (int r = 0; r < NREP; r++) v += deg_r[r * SCAN_M + i];
    degT[i] = v;
  }
  lds[tid] = v; __syncthreads();
#pragma unroll
  for (int off = 1; off < SCAN_B; off <<= 1) {
    int t = lds[tid];
    int add = (tid >= off) ? lds[tid - off] : 0;
    __syncthreads();
    lds[tid] = t + add;
    __syncthreads();
  }
  if (i < SCAN_M) seg_start[i] = lds[tid];         // local inclusive (fixed in scanC)
  if (tid == SCAN_B - 1) bsums[blockIdx.x] = lds[tid];
}

__global__ __launch_bounds__(256) void scanB_k(int* __restrict__ bsums) {
  __shared__ int lds[256];
  int tid = threadIdx.x;
  int v = (tid < SCAN_G) ? bsums[tid] : 0;
  lds[tid] = v; __syncthreads();
#pragma unroll
  for (int off = 1; off < 256; off <<= 1) {
    int t = lds[tid];
    int add = (tid >= off) ? lds[tid - off] : 0;
    __syncthreads();
    lds[tid] = t + add;
    __syncthreads();
  }
  if (tid < SCAN_G) bsums[tid] = lds[tid] - v;     // exclusive
}

__global__ __launch_bounds__(SCAN_B) void scanC(
    const int* __restrict__ degT, int* __restrict__ seg_start,
    const int* __restrict__ bsums) {
  int i = blockIdx.x * SCAN_B + threadIdx.x;
  if (i < SCAN_M) seg_start[i] = seg_start[i] - degT[i] + bsums[blockIdx.x];
}

// ---- 3. per-replica cursor init: cur_r[r][nd] = seg_start[nd] + prefix of replicas < r
__global__ __launch_bounds__(256) void cursor_init(
    const int* __restrict__ seg_start, const int* __restrict__ deg_r,
    int* __restrict__ cur_r) {
  int nd = blockIdx.x * 256 + threadIdx.x;
  if (nd >= SCAN_M) return;
  int c = seg_start[nd];
#pragma unroll
  for (int r = 0; r < NREP; r++) {
    cur_r[r * SCAN_M + nd] = c;
    c += deg_r[r * SCAN_M + nd];
  }
}

// ---- 4. fill CSR adjacency: one thread per edge-direction, one returning atomic ----
__global__ __launch_bounds__(256) void fill_kernel(
    const int* __restrict__ esrc, const int* __restrict__ edst,
    int* __restrict__ cur_r, int* __restrict__ EL) {
  unsigned ed = blockIdx.x * 256u + threadIdx.x;   // [0, 2*NE), grid exact
  int r = (ed >> 8) & (NREP - 1);
  int tgt, nbr;
  if (ed < NE) { tgt = esrc[ed]; nbr = edst[ed]; }
  else { unsigned e = ed - NE; tgt = NN + edst[e]; nbr = esrc[e]; }
  int p = atomicAdd(cur_r + r * SCAN_M + tgt, 1);
  EL[p] = nbr;
}

// ---- 5. gather-reduce: 32 lanes per node-direction, no float atomics; bf16 out ----
__global__ __launch_bounds__(256) void gather_kernel(
    const float* __restrict__ h, const int* __restrict__ EL,
    const int* __restrict__ seg_start, const int* __restrict__ degT,
    short* __restrict__ aggF, short* __restrict__ aggB) {
  unsigned gt = blockIdx.x * 256u + threadIdx.x;
  unsigned nd = gt >> 5;
  unsigned q  = gt & 31u;
  if (nd >= 2u * NN) return;
  int j = seg_start[nd];
  int end = j + degT[nd];
  f32x4 acc = {0.f, 0.f, 0.f, 0.f};
  if (j < end) {
    int nbr = EL[j];
    while (++j < end) {
      int nxt = EL[j];
      f32x4 v = *(const f32x4*)(h + (size_t)nbr * HIDDEN + q * 4);
      acc[0] += v[0]; acc[1] += v[1]; acc[2] += v[2]; acc[3] += v[3];
      nbr = nxt;
    }
    f32x4 v = *(const f32x4*)(h + (size_t)nbr * HIDDEN + q * 4);
    acc[0] += v[0]; acc[1] += v[1]; acc[2] += v[2]; acc[3] += v[3];
  }
  bf16x4 o;
#pragma unroll
  for (int t = 0; t < 4; t++) o[t] = f2bf(acc[t]);
  short* dst = ((nd < NN) ? aggF + (size_t)nd * HIDDEN
                          : aggB + (size_t)(nd - NN) * HIDDEN) + q * 4;
  *(bf16x4*)dst = o;
}

// ---- 6. fused GEMM epilogue ----
// out = relu( h@Ws^T + aggF@W^T + aggB@Wt^T + Ws_b + degF*W_b + degB*Wt_b )
__global__ __launch_bounds__(256) void gemm_fused(
    const float* __restrict__ h, const short* __restrict__ aggF,
    const short* __restrict__ aggB, const short* __restrict__ Wbf,
    const float* __restrict__ Wb, const float* __restrict__ Wsb,
    const float* __restrict__ Wtb, const int* __restrict__ degT,
    float* __restrict__ out) {
  int wave = threadIdx.x >> 6;
  int lane = threadIdx.x & 63;
  int m16  = lane & 15;
  int kq   = lane >> 4;
  int tile_row0 = blockIdx.x * 64 + wave * 16;
  int arow = tile_row0 + m16;
  bool arow_ok = arow < NN;

  bf16x8 afH[4], afF[4], afB[4];
  bf16x8 z;
#pragma unroll
  for (int j = 0; j < 8; j++) z[j] = 0;

  const float* hb = h + (size_t)arow * HIDDEN + kq * 8;
  const short* fb = aggF + (size_t)arow * HIDDEN + kq * 8;
  const short* bb = aggB + (size_t)arow * HIDDEN + kq * 8;
#pragma unroll
  for (int t = 0; t < 4; t++) {
    if (arow_ok) {
      f32x4 lo = *(const f32x4*)(hb + t * 32);
      f32x4 hi = *(const f32x4*)(hb + t * 32 + 4);
      bf16x8 r;
#pragma unroll
      for (int j = 0; j < 4; j++) { r[j] = f2bf(lo[j]); r[j + 4] = f2bf(hi[j]); }
      afH[t] = r;
      afF[t] = *(const bf16x8*)(fb + t * 32);
      afB[t] = *(const bf16x8*)(bb + t * 32);
    } else {
      afH[t] = z; afF[t] = z; afB[t] = z;
    }
  }

  int crow0 = tile_row0 + kq * 4;
  float dF[4], dB[4];
#pragma unroll
  for (int j = 0; j < 4; j++) {
    int r = crow0 + j;
    dF[j] = (r < NN) ? (float)degT[r] : 0.f;
    dB[j] = (r < NN) ? (float)degT[NN + r] : 0.f;
  }

#pragma unroll
  for (int nt = 0; nt < 8; nt++) {
    int col = nt * 16 + m16;
    f32x4 acc = {0.f, 0.f, 0.f, 0.f};
    const short* w0 = Wbf + 0 * 16384 + col * HIDDEN + kq * 8;
    const short* w1 = Wbf + 1 * 16384 + col * HIDDEN + kq * 8;
    const short* w2 = Wbf + 2 * 16384 + col * HIDDEN + kq * 8;
#pragma unroll
    for (int t = 0; t < 4; t++)
      acc = __builtin_amdgcn_mfma_f32_16x16x32_bf16(afH[t], *(const bf16x8*)(w0 + t * 32), acc, 0, 0, 0);
#pragma unroll
    for (int t = 0; t < 4; t++)
      acc = __builtin_amdgcn_mfma_f32_16x16x32_bf16(afF[t], *(const bf16x8*)(w1 + t * 32), acc, 0, 0, 0);
#pragma unroll
    for (int t = 0; t < 4; t++)
      acc = __builtin_amdgcn_mfma_f32_16x16x32_bf16(afB[t], *(const bf16x8*)(w2 + t * 32), acc, 0, 0, 0);

    float bW = Wb[col], bS = Wsb[col], bT = Wtb[col];
#pragma unroll
    for (int j = 0; j < 4; j++) {
      int r = crow0 + j;
      if (r < NN) {
        float v = acc[j] + bS + dF[j] * bW + dB[j] * bT;
        out[(size_t)r * HIDDEN + col] = fmaxf(v, 0.f);
      }
    }
  }
}

extern "C" void kernel_launch(void* const* d_in, const int* in_sizes, int n_in,
                              void* d_out, int out_size, void* d_ws, size_t ws_size,
                              hipStream_t stream) {
  const float* h    = (const float*)d_in[0];
  const int*   esrc = (const int*)d_in[1];
  const int*   edst = (const int*)d_in[2];
  const float* Ww   = (const float*)d_in[3];
  const float* Wb   = (const float*)d_in[4];
  const float* Wsw  = (const float*)d_in[5];
  const float* Wsb  = (const float*)d_in[6];
  const float* Wtw  = (const float*)d_in[7];
  const float* Wtb  = (const float*)d_in[8];
  float* out = (float*)d_out;

  char* ws = (char*)d_ws;
  // byte layout (all 16B-aligned where vector-loaded)
  int*   deg_r     = (int*)(ws + 0);            //  6,400,000  (NREP x 2NN)
  int*   degT      = (int*)(ws + 6400000);      //    800,000
  int*   seg_start = (int*)(ws + 7200000);      //    800,000
  int*   bsums     = (int*)(ws + 8000000);      //      1,024
  int*   cur_r     = (int*)(ws + 8001024);      //  6,400,000
  int*   EL        = (int*)(ws + 14401024);     //  6,400,000
  short* Wbf       = (short*)(ws + 20801024);   //     98,304
  short* aggF      = (short*)(ws + 20899328);   // 25,600,000
  short* aggB      = (short*)(ws + 46499328);   // 25,600,000  -> total ~72.1 MB

  hipMemsetAsync(deg_r, 0, (size_t)NREP * SCAN_M * sizeof(int), stream);

  convert_weights<<<192, 256, 0, stream>>>(Wsw, Ww, Wtw, Wbf);
  hist_kernel<<<EBLK, 256, 0, stream>>>(esrc, edst, deg_r);
  scanA<<<SCAN_G, SCAN_B, 0, stream>>>(deg_r, degT, seg_start, bsums);
  scanB_k<<<1, 256, 0, stream>>>(bsums);
  scanC<<<SCAN_G, SCAN_B, 0, stream>>>(degT, seg_start, bsums);
  cursor_init<<<(SCAN_M + 255) / 256, 256, 0, stream>>>(seg_start, deg_r, cur_r);
  fill_kernel<<<2 * EBLK, 256, 0, stream>>>(esrc, edst, cur_r, EL);
  gather_kernel<<<(2 * NN * 32) / 256, 256, 0, stream>>>(h, EL, seg_start, degT, aggF, aggB);
  gemm_fused<<<(NN + 63) / 64, 256, 0, stream>>>(
      h, aggF, aggB, Wbf, Wb, Wsb, Wtb, degT, out);
}